// Round 12
// baseline (261.957 us; speedup 1.0000x reference)
//
#include <hip/hip_runtime.h>

#define T_SEQ 2048
#define BATCH 2
#define HEADS 8
#define DHEAD 64
#define EMB   512

typedef __attribute__((ext_vector_type(8))) short short8;
typedef __attribute__((ext_vector_type(4))) float floatx4;
typedef __attribute__((ext_vector_type(8))) unsigned short ushort8;
typedef __attribute__((ext_vector_type(4))) unsigned short ushort4v;

// RNE convert (cold paths)
__device__ __forceinline__ unsigned short f2b(float f) {
    union { float f; unsigned u; } v; v.f = f;
    unsigned r = v.u + 0x7fffu + ((v.u >> 16) & 1u);
    return (unsigned short)(r >> 16);
}
// 1-op truncating convert (hot paths)
__device__ __forceinline__ unsigned short f2bt(float f) {
    union { float f; unsigned u; } v; v.f = f;
    return (unsigned short)(v.u >> 16);
}
__device__ __forceinline__ float b2f(unsigned short s) {
    union { unsigned u; float f; } v; v.u = ((unsigned)s) << 16; return v.f;
}
__device__ __forceinline__ short8 ld_frag(const unsigned short* p) {
    ushort4v lo = *(const ushort4v*)p;
    ushort4v hi = *(const ushort4v*)(p + 4);
    short8 r;
    r[0] = lo[0]; r[1] = lo[1]; r[2] = lo[2]; r[3] = lo[3];
    r[4] = hi[0]; r[5] = hi[1]; r[6] = hi[2]; r[7] = hi[3];
    return r;
}
__device__ __forceinline__ void st8(unsigned short* p, ushort8 v) {
    ushort4v lo = { v[0], v[1], v[2], v[3] };
    ushort4v hi = { v[4], v[5], v[6], v[7] };
    *(ushort4v*)p = lo;
    *(ushort4v*)(p + 4) = hi;
}
#define MFMA16(a, b, c) __builtin_amdgcn_mfma_f32_16x16x32_bf16(a, b, c, 0, 0, 0)

// ---------------------------------------------------------------------------
// One-shot fp32 -> bf16 conversion of all 5 tensors.
// ---------------------------------------------------------------------------
__global__ __launch_bounds__(256)
void cvt_all(const float* __restrict__ s0, const float* __restrict__ s1,
             const float* __restrict__ s2, const float* __restrict__ s3,
             const float* __restrict__ s4,
             unsigned short* __restrict__ d0, unsigned short* __restrict__ d1,
             unsigned short* __restrict__ d2, unsigned short* __restrict__ d3,
             unsigned short* __restrict__ d4)
{
    const int i = blockIdx.x * 256 + threadIdx.x;
    const float* s; unsigned short* d; int off;
    if      (i <  524288) { s = s0; d = d0; off = i; }
    else if (i <  786432) { s = s1; d = d1; off = i -  524288; }
    else if (i <  983040) { s = s2; d = d2; off = i -  786432; }
    else if (i < 1048576) { s = s3; d = d3; off = i -  983040; }
    else if (i < 1114112) { s = s4; d = d4; off = i - 1048576; }
    else return;
    const float4 v = ((const float4*)s)[off];
    ushort4v o = { f2b(v.x), f2b(v.y), f2b(v.z), f2b(v.w) };
    ((ushort4v*)d)[off] = o;
}

// ---------------------------------------------------------------------------
// Fused QKV + pos projection GEMM (448 blocks), 128x128 tiles, BK=64.
// blocks 0..383: QKV; bn<1024 -> q_s/k_s scatter; bn>=1024 -> vT via LDS
// transpose. blocks 384..447: pos -> r bf16 [R,E].
// ---------------------------------------------------------------------------
__global__ __launch_bounds__(256)
void gemm_qkv_pos(const unsigned short* __restrict__ inb, const unsigned short* __restrict__ w_inb,
                  const float* __restrict__ b_in,
                  const unsigned short* __restrict__ posb, const unsigned short* __restrict__ w_posb,
                  const float* __restrict__ b_pos,
                  unsigned short* __restrict__ q_s, unsigned short* __restrict__ k_s,
                  unsigned short* __restrict__ vT, unsigned short* __restrict__ r_b)
{
    __shared__ unsigned short shmem[17408];     // As@0, Bs@8704 | tb (128x131)
    unsigned short* As = shmem;
    unsigned short* Bs = shmem + 8704;
    unsigned short* tb = shmem;

    const int id = blockIdx.x;
    const bool isPos = (id >= 384);
    const int bx = isPos ? ((id - 384) & 3) : (id % 12);
    const int by = isPos ? ((id - 384) >> 2) : (id / 12);
    const unsigned short* A = isPos ? posb : inb;
    const unsigned short* B = isPos ? w_posb : w_inb;
    const float* bias = isPos ? b_pos : b_in;

    const int bm  = by * 128;
    const int bn  = bx * 128;
    const int tid = threadIdx.x;
    const int lane = tid & 63, w = tid >> 6;
    const int m16 = lane & 15, quad = lane >> 4;
    const int wm = (w & 1) * 64, wn = (w >> 1) * 64;

    floatx4 acc[4][4];
    #pragma unroll
    for (int i = 0; i < 4; ++i)
        #pragma unroll
        for (int j = 0; j < 4; ++j) acc[i][j] = (floatx4){0.f, 0.f, 0.f, 0.f};

    for (int k0 = 0; k0 < 512; k0 += 64) {
        #pragma unroll
        for (int s = tid; s < 1024; s += 256) {
            const int row = s >> 3, c = (s & 7) * 8;
            st8(&As[row * 68 + c], *(const ushort8*)(A + (size_t)(bm + row) * 512 + k0 + c));
            st8(&Bs[row * 68 + c], *(const ushort8*)(B + (size_t)(bn + row) * 512 + k0 + c));
        }
        __syncthreads();
        #pragma unroll
        for (int ks = 0; ks < 2; ++ks) {
            short8 af[4], bf[4];
            #pragma unroll
            for (int f = 0; f < 4; ++f) {
                af[f] = ld_frag(&As[(wm + f * 16 + m16) * 68 + ks * 32 + quad * 8]);
                bf[f] = ld_frag(&Bs[(wn + f * 16 + m16) * 68 + ks * 32 + quad * 8]);
            }
            #pragma unroll
            for (int fm = 0; fm < 4; ++fm)
                #pragma unroll
                for (int fn = 0; fn < 4; ++fn)
                    acc[fm][fn] = MFMA16(af[fm], bf[fn], acc[fm][fn]);
        }
        __syncthreads();
    }

    if (isPos) {
        #pragma unroll
        for (int fn = 0; fn < 4; ++fn) {
            const int n = bn + wn + fn * 16 + m16;
            const float bv = bias[n];
            #pragma unroll
            for (int fm = 0; fm < 4; ++fm)
                #pragma unroll
                for (int rgi = 0; rgi < 4; ++rgi) {
                    const int m = bm + wm + fm * 16 + quad * 4 + rgi;
                    r_b[(size_t)m * EMB + n] = f2b(acc[fm][fn][rgi] + bv);
                }
        }
    } else if (bn < 1024) {
        #pragma unroll
        for (int fn = 0; fn < 4; ++fn) {
            const int n = bn + wn + fn * 16 + m16;
            const float bv = bias[n];
            const int reg = n >> 9, c = n & 511, h = c >> 6, dd = c & 63;
            unsigned short* dst = reg == 0 ? q_s : k_s;
            #pragma unroll
            for (int fm = 0; fm < 4; ++fm)
                #pragma unroll
                for (int rgi = 0; rgi < 4; ++rgi) {
                    const int m = bm + wm + fm * 16 + quad * 4 + rgi;
                    const int t = m >> 1, b = m & 1;
                    dst[((size_t)(b * HEADS + h) * T_SEQ + t) * DHEAD + dd] = f2b(acc[fm][fn][rgi] + bv);
                }
        }
    } else {
        #pragma unroll
        for (int fn = 0; fn < 4; ++fn) {
            const int nl = wn + fn * 16 + m16;
            const float bv = bias[bn + nl];
            #pragma unroll
            for (int fm = 0; fm < 4; ++fm)
                #pragma unroll
                for (int rgi = 0; rgi < 4; ++rgi) {
                    const int ml = wm + fm * 16 + quad * 4 + rgi;
                    tb[nl * 131 + ml] = f2b(acc[fm][fn][rgi] + bv);
                }
        }
        __syncthreads();
        const int t0g = bm >> 1;
        for (int s2 = tid; s2 < 2048; s2 += 256) {
            const int nl = s2 >> 4;
            const int bsel = (s2 >> 3) & 1;
            const int j = s2 & 7;
            ushort8 o;
            #pragma unroll
            for (int k = 0; k < 8; ++k)
                o[k] = tb[nl * 131 + ((j * 8 + k) * 2 + bsel)];
            const int c = bn + nl - 1024, h = c >> 6, dd = c & 63;
            *(ushort8*)(vT + ((size_t)(bsel * HEADS + h) * DHEAD + dd) * T_SEQ + t0g + j * 8) = o;
        }
    }
}

// ---------------------------------------------------------------------------
// Output GEMM: ctx bf16 [4096,512] x w_out -> fp32 out. 128x128, BK=64.
// ---------------------------------------------------------------------------
__global__ __launch_bounds__(256)
void gemm_out(const unsigned short* __restrict__ A, const unsigned short* __restrict__ B,
              const float* __restrict__ bias, float* __restrict__ out)
{
    __shared__ unsigned short As[128 * 68];
    __shared__ unsigned short Bs[128 * 68];
    const int bm  = blockIdx.y * 128;
    const int bn  = blockIdx.x * 128;
    const int tid = threadIdx.x;
    const int lane = tid & 63, w = tid >> 6;
    const int m16 = lane & 15, quad = lane >> 4;
    const int wm = (w & 1) * 64, wn = (w >> 1) * 64;

    floatx4 acc[4][4];
    #pragma unroll
    for (int i = 0; i < 4; ++i)
        #pragma unroll
        for (int j = 0; j < 4; ++j) acc[i][j] = (floatx4){0.f, 0.f, 0.f, 0.f};

    for (int k0 = 0; k0 < 512; k0 += 64) {
        #pragma unroll
        for (int s = tid; s < 1024; s += 256) {
            const int row = s >> 3, c = (s & 7) * 8;
            st8(&As[row * 68 + c], *(const ushort8*)(A + (size_t)(bm + row) * 512 + k0 + c));
            st8(&Bs[row * 68 + c], *(const ushort8*)(B + (size_t)(bn + row) * 512 + k0 + c));
        }
        __syncthreads();
        #pragma unroll
        for (int ks = 0; ks < 2; ++ks) {
            short8 af[4], bf[4];
            #pragma unroll
            for (int f = 0; f < 4; ++f) {
                af[f] = ld_frag(&As[(wm + f * 16 + m16) * 68 + ks * 32 + quad * 8]);
                bf[f] = ld_frag(&Bs[(wn + f * 16 + m16) * 68 + ks * 32 + quad * 8]);
            }
            #pragma unroll
            for (int fm = 0; fm < 4; ++fm)
                #pragma unroll
                for (int fn = 0; fn < 4; ++fn)
                    acc[fm][fn] = MFMA16(af[fm], bf[fn], acc[fm][fn]);
        }
        __syncthreads();
    }

    #pragma unroll
    for (int fn = 0; fn < 4; ++fn) {
        const int n = bn + wn + fn * 16 + m16;
        const float bv = bias[n];
        #pragma unroll
        for (int fm = 0; fm < 4; ++fm)
            #pragma unroll
            for (int rgi = 0; rgi < 4; ++rgi) {
                const int m = bm + wm + fm * 16 + quad * 4 + rgi;
                out[(size_t)m * EMB + n] = acc[fm][fn][rgi] + bv;
            }
    }
}

// ---------------------------------------------------------------------------
// Fused MFMA attention, COLUMN-SPLIT AC/QR: waves own s/window cols (wave w
// -> cols 16w..16w+15, u = 16w+m16 is per-lane constant); all 64 q-rows'
// A-frags live in registers (a_*[4 rowchunks][2 ks]). Cuts per-wave LDS frag
// reads for AC+QR from 32 b64 to 8 b64 (LDS pipe was ~75% busy).
// PV stays row-split (A-operand P is in LDS; no redundancy win).
// Double-buffered staging, register prefetch, no-max exp2 softmax, per-lane
// l partials (16) reduced once at epilogue via LDS.
//   bd[t][s] = QR[t][T-1-t+s] (s<=t) | 0 (s==t+1) | QR[t+1][s-t-2] (s>=t+2)
// LDS (u16): k@0 (2x4352) v@8704 (2x4352) rp@17408 (2x4352) ring@26112
// (64x133, [i][slot]). 69,248 B -> 2 blocks/CU. lsum reuses ring at epilogue.
// ---------------------------------------------------------------------------
__global__ __launch_bounds__(256)
void attn_mfma(const unsigned short* __restrict__ qg_, const unsigned short* __restrict__ kg_,
               const unsigned short* __restrict__ vtg_, const unsigned short* __restrict__ rg_,
               const float* __restrict__ rwb, const float* __restrict__ rrb,
               unsigned short* __restrict__ ctx)
{
    const int T   = T_SEQ;
    const int tb  = blockIdx.x;
    const int t0  = tb * 64;
    const int bh  = blockIdx.y;
    const int h   = bh & 7;
    const int b   = bh >> 3;
    const int tid = threadIdx.x;
    const int lane = tid & 63;
    const int w    = tid >> 6;
    const int m16  = lane & 15;
    const int quad = lane >> 4;
    const int iq   = quad * 4;            // row offset within a 16-row chunk
    const int u    = 16 * w + m16;        // this lane's s/window column
    const int ibase = 16 * w + iq;        // PV/epilogue row base

    __shared__ unsigned short lds[34624];
    unsigned short* ring  = lds + 26112;     // [i][slot], stride 133
    unsigned short* qrw_s = lds;             // pre-loop alias (k buf 0)
    unsigned short* qrr_s = lds + 8704;      // pre-loop alias (v buf 0, 65 rows)

    const unsigned short* qg  = qg_  + ((size_t)bh * T + t0) * DHEAD;
    const unsigned short* kg  = kg_  + (size_t)bh * T * DHEAD;
    const unsigned short* vtg = vtg_ + (size_t)bh * DHEAD * T;
    const unsigned short* rg  = rg_  + h * DHEAD;

    // ---- stage q tiles: (q + bias) * 0.125 * log2e ----
    const float QSCALE = 0.125f * 1.44269504089f;
    for (int idx = tid; idx < 65 * 16; idx += 256) {
        const int row = idx >> 4, c = (idx & 15) << 2;
        ushort4v qv = {0, 0, 0, 0};
        if (t0 + row < T) qv = *(const ushort4v*)(qg + row * DHEAD + c);
        const float4 rr = *(const float4*)(rrb + h * DHEAD + c);
        qrr_s[row * 68 + c + 0] = f2b((b2f(qv[0]) + rr.x) * QSCALE);
        qrr_s[row * 68 + c + 1] = f2b((b2f(qv[1]) + rr.y) * QSCALE);
        qrr_s[row * 68 + c + 2] = f2b((b2f(qv[2]) + rr.z) * QSCALE);
        qrr_s[row * 68 + c + 3] = f2b((b2f(qv[3]) + rr.w) * QSCALE);
        if (row < 64) {
            const float4 rw = *(const float4*)(rwb + h * DHEAD + c);
            qrw_s[row * 68 + c + 0] = f2b((b2f(qv[0]) + rw.x) * QSCALE);
            qrw_s[row * 68 + c + 1] = f2b((b2f(qv[1]) + rw.y) * QSCALE);
            qrw_s[row * 68 + c + 2] = f2b((b2f(qv[2]) + rw.z) * QSCALE);
            qrw_s[row * 68 + c + 3] = f2b((b2f(qv[3]) + rw.w) * QSCALE);
        }
    }
    __syncthreads();

    // A-fragments for ALL 64 rows (4 rowchunks), per wave (identical across waves)
    short8 a_ac[4][2], a_qrl[4][2], a_qru[4][2];
    #pragma unroll
    for (int rc = 0; rc < 4; ++rc) {
        const unsigned short* p0 = &qrw_s[(rc * 16 + m16) * 68 + quad * 8];
        a_ac[rc][0]  = ld_frag(p0);  a_ac[rc][1]  = ld_frag(p0 + 32);
        const unsigned short* p1 = &qrr_s[(rc * 16 + m16) * 68 + quad * 8];
        a_qrl[rc][0] = ld_frag(p1);  a_qrl[rc][1] = ld_frag(p1 + 32);
        const unsigned short* p2 = &qrr_s[(rc * 16 + 1 + m16) * 68 + quad * 8];
        a_qru[rc][0] = ld_frag(p2);  a_qru[rc][1] = ld_frag(p2 + 32);
    }

    const int srow0 = tid >> 3,          scol0 = (tid & 7) * 8;
    const int srow1 = (tid + 256) >> 3,  scol1 = (tid & 7) * 8;

    ushort8 kr[2], vr[2], rr8[2];
    auto prefetch = [&](int s0n) {
        const bool ln = (s0n <= t0);
        const int jb = (ln ? (s0n + T - t0 - 64) : (s0n - t0 - 65)) + 64;
        int j0 = jb + srow0; j0 = j0 < 0 ? 0 : (j0 > T - 1 ? T - 1 : j0);
        int j1 = jb + srow1; j1 = j1 < 0 ? 0 : (j1 > T - 1 ? T - 1 : j1);
        kr[0]  = *(const ushort8*)(kg + (size_t)(s0n + srow0) * DHEAD + scol0);
        kr[1]  = *(const ushort8*)(kg + (size_t)(s0n + srow1) * DHEAD + scol1);
        vr[0]  = *(const ushort8*)(vtg + (size_t)srow0 * T + s0n + scol0);
        vr[1]  = *(const ushort8*)(vtg + (size_t)srow1 * T + s0n + scol1);
        rr8[0] = *(const ushort8*)(rg + (size_t)j0 * EMB + scol0);
        rr8[1] = *(const ushort8*)(rg + (size_t)j1 * EMB + scol1);
    };
    auto store_bufs = [&](int q) {
        unsigned short* kb = lds + q * 4352;
        unsigned short* vb = lds + 8704 + q * 4352;
        unsigned short* rb = lds + 17408 + q * 4352;
        st8(&kb[srow0 * 68 + scol0], kr[0]);
        st8(&kb[srow1 * 68 + scol1], kr[1]);
        st8(&vb[srow0 * 68 + scol0], vr[0]);
        st8(&vb[srow1 * 68 + scol1], vr[1]);
        st8(&rb[srow0 * 68 + scol0], rr8[0]);
        st8(&rb[srow1 * 68 + scol1], rr8[1]);
    };
    auto stage_to = [&](unsigned short* dstb, int jbase) {
        #pragma unroll
        for (int idx = tid; idx < 512; idx += 256) {
            const int row = idx >> 3, c = (idx & 7) * 8;
            int j = jbase + row; j = j < 0 ? 0 : (j > T - 1 ? T - 1 : j);
            st8(&dstb[row * 68 + c], *(const ushort8*)(rg + (size_t)j * EMB + c));
        }
    };
    // column-split QR: this wave computes its 16 window cols for all 64 rows
    auto qr_half = [&](const unsigned short* rsb, const short8 (*aq)[2], int slotbase) {
        short8 rfr0 = ld_frag(&rsb[(16 * w + m16) * 68 + quad * 8]);
        short8 rfr1 = ld_frag(&rsb[(16 * w + m16) * 68 + 32 + quad * 8]);
        #pragma unroll
        for (int rc = 0; rc < 4; ++rc) {
            floatx4 q4 = (floatx4){0.f, 0.f, 0.f, 0.f};
            q4 = MFMA16(aq[rc][0], rfr0, q4);
            q4 = MFMA16(aq[rc][1], rfr1, q4);
            #pragma unroll
            for (int rgi = 0; rgi < 4; ++rgi)
                ring[(rc * 16 + iq + rgi) * 133 + slotbase + u] = f2bt(q4[rgi]);
        }
    };

    floatx4 O[4];
    float lrun[16];
    #pragma unroll
    for (int ct = 0; ct < 4; ++ct) O[ct] = (floatx4){0.f, 0.f, 0.f, 0.f};
    #pragma unroll
    for (int i = 0; i < 16; ++i) lrun[i] = 0.f;

    // ---- prologue ----
    {
        stage_to(lds + 17408 + 4352, T - t0 - 64);
        prefetch(0);
        __syncthreads();
        qr_half(lds + 17408 + 4352, a_qrl, 0);
        store_bufs(0);
        __syncthreads();
    }

    for (int na = 0; na < T / 64; ++na) {
        const int s0 = na * 64;
        const int p = na & 1;
        unsigned short* kb = lds + p * 4352;
        unsigned short* vb = lds + 8704 + p * 4352;
        unsigned short* rp = lds + 17408 + p * 4352;
        const bool lower = (s0 <= t0);
        const int nph    = lower ? (s0 >> 6) : ((s0 - t0) >> 6);
        const int rbase  = (nph & 1) * 64;
        const int wbase  = 64 - rbase;
        const bool hasNext = (na + 1 < T / 64);

        // ---- phase A: AC (col-split) + QR (col-split) + prefetch ----
        floatx4 acf[4];
        {
            short8 kfr0 = ld_frag(&kb[(16 * w + m16) * 68 + quad * 8]);
            short8 kfr1 = ld_frag(&kb[(16 * w + m16) * 68 + 32 + quad * 8]);
            #pragma unroll
            for (int rc = 0; rc < 4; ++rc) {
                acf[rc] = (floatx4){0.f, 0.f, 0.f, 0.f};
                acf[rc] = MFMA16(a_ac[rc][0], kfr0, acf[rc]);
                acf[rc] = MFMA16(a_ac[rc][1], kfr1, acf[rc]);
            }
        }
        qr_half(rp, lower ? a_qrl : a_qru, wbase);
        if (hasNext) prefetch(s0 + 64);
        __syncthreads();                       // B1

        // ---- phase B: assemble + softmax + P write + staging store ----
        if (s0 != t0) {
            #pragma unroll
            for (int rc = 0; rc < 4; ++rc) {
                #pragma unroll
                for (int rgi = 0; rgi < 4; ++rgi) {
                    const int i = rc * 16 + iq + rgi;
                    const int slot = ((63 - i + u) + rbase) & 127;
                    acf[rc][rgi] += b2f(ring[i * 133 + slot]);
                }
            }
            // garbage element (i=63, u=0): w==0, lane 48 (quad 3, m16 0), rc=3, rgi=3
            if (s0 == t0 + 64 && w == 0 && lane == 48)
                acf[3][3] -= b2f(ring[63 * 133 + (rbase & 127)]);
        } else {
            // DIAG pass 1: lower-masked
            #pragma unroll
            for (int rc = 0; rc < 4; ++rc) {
                #pragma unroll
                for (int rgi = 0; rgi < 4; ++rgi) {
                    const int i = rc * 16 + iq + rgi;
                    if (u <= i) acf[rc][rgi] += b2f(ring[i * 133 + (((63 - i + u) + rbase) & 127)]);
                }
            }
            // DIAG pass 2: upper prologue into rp[1-p] + ring slots 64..127
            unsigned short* rpo = lds + 17408 + (1 - p) * 4352;
            __syncthreads();                   // Bd1
            stage_to(rpo, -1);
            __syncthreads();                   // Bd2
            qr_half(rpo, a_qru, 64);
            __syncthreads();                   // Bd3
            #pragma unroll
            for (int rc = 0; rc < 4; ++rc) {
                #pragma unroll
                for (int rgi = 0; rgi < 4; ++rgi) {
                    const int i = rc * 16 + iq + rgi;
                    if (u >= i + 2) acf[rc][rgi] += b2f(ring[i * 133 + 63 - i + u]);
                }
            }
        }

        // no-max exp2 softmax, per-lane partial l (one u per lane)
        #pragma unroll
        for (int rc = 0; rc < 4; ++rc) {
            #pragma unroll
            for (int rgi = 0; rgi < 4; ++rgi) {
                const float pv = exp2f(acf[rc][rgi]);
                acf[rc][rgi] = pv;
                lrun[rc * 4 + rgi] += pv;
            }
        }
        // P -> rp (r reads done at B1): P[i][u]
        #pragma unroll
        for (int rc = 0; rc < 4; ++rc)
            #pragma unroll
            for (int rgi = 0; rgi < 4; ++rgi)
                rp[(rc * 16 + iq + rgi) * 68 + u] = f2bt(acf[rc][rgi]);
        if (hasNext) store_bufs(1 - p);
        __syncthreads();                       // B2

        // ---- PV (row-split, unchanged) ----
        short8 ap[2];
        {
            const unsigned short* pp = &rp[(16 * w + m16) * 68 + quad * 8];
            ap[0] = ld_frag(pp); ap[1] = ld_frag(pp + 32);
        }
        #pragma unroll
        for (int ct = 0; ct < 4; ++ct) {
            #pragma unroll
            for (int ks = 0; ks < 2; ++ks) {
                short8 bfr = ld_frag(&vb[(16 * ct + m16) * 68 + ks * 32 + quad * 8]);
                O[ct] = MFMA16(ap[ks], bfr, O[ct]);
            }
        }
    }

    // ---- epilogue: cross-lane + cross-wave l reduction (lsum over ring) ----
    float* lsum = (float*)ring;    // 4 waves x 64 rows, 1 KB, ring is dead
    #pragma unroll
    for (int rc = 0; rc < 4; ++rc) {
        #pragma unroll
        for (int rgi = 0; rgi < 4; ++rgi) {
            float v = lrun[rc * 4 + rgi];
            v += __shfl_xor(v, 1); v += __shfl_xor(v, 2);
            v += __shfl_xor(v, 4); v += __shfl_xor(v, 8);
            if (m16 == 0) lsum[w * 64 + rc * 16 + iq + rgi] = v;
        }
    }
    __syncthreads();
    #pragma unroll
    for (int rgi = 0; rgi < 4; ++rgi) {
        const int i = ibase + rgi;
        const float l = lsum[i] + lsum[64 + i] + lsum[128 + i] + lsum[192 + i];
        const float inv = 1.f / l;
        const int t = t0 + i;
        #pragma unroll
        for (int ct = 0; ct < 4; ++ct)
            ctx[((size_t)t * BATCH + b) * EMB + h * DHEAD + 16 * ct + m16] = f2bt(O[ct][rgi] * inv);
    }
}

// ---------------------------------------------------------------------------
// Workspace (ushort offsets), 15,990,784 ush = 31.98 MB:
//   0 inb | 2097152 posb | 3145728 w_inb | 3932160 w_posb | 4194304 free |
//   6291456 w_outb | 6553600 q_s | 8650752 k_s | 10747904 vT | 12845056 r_b |
//   13893632 ctx_b
// ---------------------------------------------------------------------------
extern "C" void kernel_launch(void* const* d_in, const int* in_sizes, int n_in,
                              void* d_out, int out_size, void* d_ws, size_t ws_size,
                              hipStream_t stream)
{
    const float* input = (const float*)d_in[0];
    const float* pos   = (const float*)d_in[1];
    const float* w_in  = (const float*)d_in[2];
    const float* w_out = (const float*)d_in[3];
    const float* w_pos = (const float*)d_in[4];
    const float* b_in  = (const float*)d_in[5];
    const float* b_out = (const float*)d_in[6];
    const float* b_pos = (const float*)d_in[7];
    const float* rwb   = (const float*)d_in[8];
    const float* rrb   = (const float*)d_in[9];

    unsigned short* ws     = (unsigned short*)d_ws;
    unsigned short* inb    = ws;
    unsigned short* posb   = ws + 2097152;
    unsigned short* w_inb  = ws + 3145728;
    unsigned short* w_posb = ws + 3932160;
    unsigned short* w_outb = ws + 6291456;
    unsigned short* q_s    = ws + 6553600;
    unsigned short* k_s    = ws + 8650752;
    unsigned short* vT     = ws + 10747904;
    unsigned short* r_b    = ws + 12845056;
    unsigned short* ctx_b  = ws + 13893632;

    cvt_all<<<4352, 256, 0, stream>>>(input, pos, w_in, w_pos, w_out,
                                      inb, posb, w_inb, w_posb, w_outb);
    gemm_qkv_pos<<<448, 256, 0, stream>>>(inb, w_inb, b_in, posb, w_posb, b_pos,
                                          q_s, k_s, vT, r_b);
    attn_mfma<<<dim3(32, 16), 256, 0, stream>>>(q_s, k_s, vT, r_b, rwb, rrb, ctx_b);
    gemm_out<<<dim3(4, 32), 256, 0, stream>>>(ctx_b, w_outb, b_out, (float*)d_out);
}

// Round 13
// 194.787 us; speedup vs baseline: 1.3448x; 1.3448x over previous
//
#include <hip/hip_runtime.h>

#define T_SEQ 2048
#define BATCH 2
#define HEADS 8
#define DHEAD 64
#define EMB   512

typedef __attribute__((ext_vector_type(8))) short short8;
typedef __attribute__((ext_vector_type(4))) float floatx4;
typedef __attribute__((ext_vector_type(8))) unsigned short ushort8;
typedef __attribute__((ext_vector_type(4))) unsigned short ushort4v;

// RNE convert (cold paths)
__device__ __forceinline__ unsigned short f2b(float f) {
    union { float f; unsigned u; } v; v.f = f;
    unsigned r = v.u + 0x7fffu + ((v.u >> 16) & 1u);
    return (unsigned short)(r >> 16);
}
// 1-op truncating convert (hot paths)
__device__ __forceinline__ unsigned short f2bt(float f) {
    union { float f; unsigned u; } v; v.f = f;
    return (unsigned short)(v.u >> 16);
}
__device__ __forceinline__ float b2f(unsigned short s) {
    union { unsigned u; float f; } v; v.u = ((unsigned)s) << 16; return v.f;
}
__device__ __forceinline__ short8 ld_frag(const unsigned short* p) {
    ushort4v lo = *(const ushort4v*)p;
    ushort4v hi = *(const ushort4v*)(p + 4);
    short8 r;
    r[0] = lo[0]; r[1] = lo[1]; r[2] = lo[2]; r[3] = lo[3];
    r[4] = hi[0]; r[5] = hi[1]; r[6] = hi[2]; r[7] = hi[3];
    return r;
}
__device__ __forceinline__ void st8(unsigned short* p, ushort8 v) {
    ushort4v lo = { v[0], v[1], v[2], v[3] };
    ushort4v hi = { v[4], v[5], v[6], v[7] };
    *(ushort4v*)p = lo;
    *(ushort4v*)(p + 4) = hi;
}
#define MFMA16(a, b, c) __builtin_amdgcn_mfma_f32_16x16x32_bf16(a, b, c, 0, 0, 0)

// ---------------------------------------------------------------------------
// One-shot fp32 -> bf16 conversion of all 5 tensors.
// ---------------------------------------------------------------------------
__global__ __launch_bounds__(256)
void cvt_all(const float* __restrict__ s0, const float* __restrict__ s1,
             const float* __restrict__ s2, const float* __restrict__ s3,
             const float* __restrict__ s4,
             unsigned short* __restrict__ d0, unsigned short* __restrict__ d1,
             unsigned short* __restrict__ d2, unsigned short* __restrict__ d3,
             unsigned short* __restrict__ d4)
{
    const int i = blockIdx.x * 256 + threadIdx.x;
    const float* s; unsigned short* d; int off;
    if      (i <  524288) { s = s0; d = d0; off = i; }
    else if (i <  786432) { s = s1; d = d1; off = i -  524288; }
    else if (i <  983040) { s = s2; d = d2; off = i -  786432; }
    else if (i < 1048576) { s = s3; d = d3; off = i -  983040; }
    else if (i < 1114112) { s = s4; d = d4; off = i - 1048576; }
    else return;
    const float4 v = ((const float4*)s)[off];
    ushort4v o = { f2b(v.x), f2b(v.y), f2b(v.z), f2b(v.w) };
    ((ushort4v*)d)[off] = o;
}

// ---------------------------------------------------------------------------
// Fused QKV + pos projection GEMM (448 blocks), 128x128 tiles, BK=64,
// double-buffered LDS + register prefetch: 1 barrier per k-iter (8 total).
// blocks 0..383: QKV; bn<1024 -> q_s/k_s scatter; bn>=1024 -> vT via LDS
// transpose (tb aliases buf0; final k-iter reads buf1 -> disjoint).
// blocks 384..447: pos -> r bf16 [R,E].
// LDS: As0@0 Bs0@8704 As1@17408 Bs1@26112 (each 128x68) = 69,632 B -> 2/CU.
// ---------------------------------------------------------------------------
__global__ __launch_bounds__(256)
void gemm_qkv_pos(const unsigned short* __restrict__ inb, const unsigned short* __restrict__ w_inb,
                  const float* __restrict__ b_in,
                  const unsigned short* __restrict__ posb, const unsigned short* __restrict__ w_posb,
                  const float* __restrict__ b_pos,
                  unsigned short* __restrict__ q_s, unsigned short* __restrict__ k_s,
                  unsigned short* __restrict__ vT, unsigned short* __restrict__ r_b)
{
    __shared__ unsigned short shmem[34816];
    unsigned short* tb = shmem;                 // 128x131 transpose buf (aliases buf0)

    const int id = blockIdx.x;
    const bool isPos = (id >= 384);
    const int bx = isPos ? ((id - 384) & 3) : (id % 12);
    const int by = isPos ? ((id - 384) >> 2) : (id / 12);
    const unsigned short* A = isPos ? posb : inb;
    const unsigned short* B = isPos ? w_posb : w_inb;
    const float* bias = isPos ? b_pos : b_in;

    const int bm  = by * 128;
    const int bn  = bx * 128;
    const int tid = threadIdx.x;
    const int lane = tid & 63, w = tid >> 6;
    const int m16 = lane & 15, quad = lane >> 4;
    const int wm = (w & 1) * 64, wn = (w >> 1) * 64;
    const int srow = tid >> 1, scol = (tid & 1) * 32;   // staging: 2 ushort8 each for A,B per chunk

    floatx4 acc[4][4];
    #pragma unroll
    for (int i = 0; i < 4; ++i)
        #pragma unroll
        for (int j = 0; j < 4; ++j) acc[i][j] = (floatx4){0.f, 0.f, 0.f, 0.f};

    ushort8 ar[4], br[4];
    auto fetch = [&](int k0) {
        #pragma unroll
        for (int c = 0; c < 2; ++c) {
            ar[c * 2 + 0] = *(const ushort8*)(A + (size_t)(bm + srow) * 512 + k0 + scol + c * 8);
            ar[c * 2 + 1] = *(const ushort8*)(A + (size_t)(bm + 128 + srow - 128) * 512 + k0 + scol + c * 8); // dummy same row to keep shape
        }
        // simpler: 2 chunks of A and 2 of B per thread (128 rows x 64 cols / 256 thr = 32 elem = 4 ushort8? no: 128*64/256 = 32 elems = 4 ushort8 total for A)
        ar[0] = *(const ushort8*)(A + (size_t)(bm + srow) * 512 + k0 + scol);
        ar[1] = *(const ushort8*)(A + (size_t)(bm + srow) * 512 + k0 + scol + 8);
        ar[2] = *(const ushort8*)(A + (size_t)(bm + srow) * 512 + k0 + scol + 16);
        ar[3] = *(const ushort8*)(A + (size_t)(bm + srow) * 512 + k0 + scol + 24);
        br[0] = *(const ushort8*)(B + (size_t)(bn + srow) * 512 + k0 + scol);
        br[1] = *(const ushort8*)(B + (size_t)(bn + srow) * 512 + k0 + scol + 8);
        br[2] = *(const ushort8*)(B + (size_t)(bn + srow) * 512 + k0 + scol + 16);
        br[3] = *(const ushort8*)(B + (size_t)(bn + srow) * 512 + k0 + scol + 24);
    };
    auto store_stage = [&](int q) {
        unsigned short* As = shmem + q * 17408;
        unsigned short* Bs = shmem + q * 17408 + 8704;
        st8(&As[srow * 68 + scol +  0], ar[0]);
        st8(&As[srow * 68 + scol +  8], ar[1]);
        st8(&As[srow * 68 + scol + 16], ar[2]);
        st8(&As[srow * 68 + scol + 24], ar[3]);
        st8(&Bs[srow * 68 + scol +  0], br[0]);
        st8(&Bs[srow * 68 + scol +  8], br[1]);
        st8(&Bs[srow * 68 + scol + 16], br[2]);
        st8(&Bs[srow * 68 + scol + 24], br[3]);
    };

    fetch(0);
    store_stage(0);
    __syncthreads();

    for (int kt = 0; kt < 8; ++kt) {
        const int p = kt & 1;
        unsigned short* As = shmem + p * 17408;
        unsigned short* Bs = shmem + p * 17408 + 8704;
        if (kt + 1 < 8) fetch((kt + 1) * 64);
        #pragma unroll
        for (int ks = 0; ks < 2; ++ks) {
            short8 af[4], bf[4];
            #pragma unroll
            for (int f = 0; f < 4; ++f) {
                af[f] = ld_frag(&As[(wm + f * 16 + m16) * 68 + ks * 32 + quad * 8]);
                bf[f] = ld_frag(&Bs[(wn + f * 16 + m16) * 68 + ks * 32 + quad * 8]);
            }
            #pragma unroll
            for (int fm = 0; fm < 4; ++fm)
                #pragma unroll
                for (int fn = 0; fn < 4; ++fn)
                    acc[fm][fn] = MFMA16(af[fm], bf[fn], acc[fm][fn]);
        }
        if (kt + 1 < 8) store_stage(1 - p);
        __syncthreads();
    }

    if (isPos) {
        #pragma unroll
        for (int fn = 0; fn < 4; ++fn) {
            const int n = bn + wn + fn * 16 + m16;
            const float bv = bias[n];
            #pragma unroll
            for (int fm = 0; fm < 4; ++fm)
                #pragma unroll
                for (int rgi = 0; rgi < 4; ++rgi) {
                    const int m = bm + wm + fm * 16 + quad * 4 + rgi;
                    r_b[(size_t)m * EMB + n] = f2b(acc[fm][fn][rgi] + bv);
                }
        }
    } else if (bn < 1024) {
        #pragma unroll
        for (int fn = 0; fn < 4; ++fn) {
            const int n = bn + wn + fn * 16 + m16;
            const float bv = bias[n];
            const int reg = n >> 9, c = n & 511, h = c >> 6, dd = c & 63;
            unsigned short* dst = reg == 0 ? q_s : k_s;
            #pragma unroll
            for (int fm = 0; fm < 4; ++fm)
                #pragma unroll
                for (int rgi = 0; rgi < 4; ++rgi) {
                    const int m = bm + wm + fm * 16 + quad * 4 + rgi;
                    const int t = m >> 1, b = m & 1;
                    dst[((size_t)(b * HEADS + h) * T_SEQ + t) * DHEAD + dd] = f2b(acc[fm][fn][rgi] + bv);
                }
        }
    } else {
        #pragma unroll
        for (int fn = 0; fn < 4; ++fn) {
            const int nl = wn + fn * 16 + m16;
            const float bv = bias[bn + nl];
            #pragma unroll
            for (int fm = 0; fm < 4; ++fm)
                #pragma unroll
                for (int rgi = 0; rgi < 4; ++rgi) {
                    const int ml = wm + fm * 16 + quad * 4 + rgi;
                    tb[nl * 131 + ml] = f2b(acc[fm][fn][rgi] + bv);
                }
        }
        __syncthreads();
        const int t0g = bm >> 1;
        for (int s2 = tid; s2 < 2048; s2 += 256) {
            const int nl = s2 >> 4;
            const int bsel = (s2 >> 3) & 1;
            const int j = s2 & 7;
            ushort8 o;
            #pragma unroll
            for (int k = 0; k < 8; ++k)
                o[k] = tb[nl * 131 + ((j * 8 + k) * 2 + bsel)];
            const int c = bn + nl - 1024, h = c >> 6, dd = c & 63;
            *(ushort8*)(vT + ((size_t)(bsel * HEADS + h) * DHEAD + dd) * T_SEQ + t0g + j * 8) = o;
        }
    }
}

// ---------------------------------------------------------------------------
// Output GEMM: ctx bf16 [4096,512] x w_out -> fp32 out. 128x128, BK=64,
// double-buffered + register prefetch (1 barrier/k-iter).
// ---------------------------------------------------------------------------
__global__ __launch_bounds__(256)
void gemm_out(const unsigned short* __restrict__ A, const unsigned short* __restrict__ B,
              const float* __restrict__ bias, float* __restrict__ out)
{
    __shared__ unsigned short shmem[34816];
    const int bm  = blockIdx.y * 128;
    const int bn  = blockIdx.x * 128;
    const int tid = threadIdx.x;
    const int lane = tid & 63, w = tid >> 6;
    const int m16 = lane & 15, quad = lane >> 4;
    const int wm = (w & 1) * 64, wn = (w >> 1) * 64;
    const int srow = tid >> 1, scol = (tid & 1) * 32;

    floatx4 acc[4][4];
    #pragma unroll
    for (int i = 0; i < 4; ++i)
        #pragma unroll
        for (int j = 0; j < 4; ++j) acc[i][j] = (floatx4){0.f, 0.f, 0.f, 0.f};

    ushort8 ar[4], br[4];
    auto fetch = [&](int k0) {
        ar[0] = *(const ushort8*)(A + (size_t)(bm + srow) * 512 + k0 + scol);
        ar[1] = *(const ushort8*)(A + (size_t)(bm + srow) * 512 + k0 + scol + 8);
        ar[2] = *(const ushort8*)(A + (size_t)(bm + srow) * 512 + k0 + scol + 16);
        ar[3] = *(const ushort8*)(A + (size_t)(bm + srow) * 512 + k0 + scol + 24);
        br[0] = *(const ushort8*)(B + (size_t)(bn + srow) * 512 + k0 + scol);
        br[1] = *(const ushort8*)(B + (size_t)(bn + srow) * 512 + k0 + scol + 8);
        br[2] = *(const ushort8*)(B + (size_t)(bn + srow) * 512 + k0 + scol + 16);
        br[3] = *(const ushort8*)(B + (size_t)(bn + srow) * 512 + k0 + scol + 24);
    };
    auto store_stage = [&](int q) {
        unsigned short* As = shmem + q * 17408;
        unsigned short* Bs = shmem + q * 17408 + 8704;
        st8(&As[srow * 68 + scol +  0], ar[0]);
        st8(&As[srow * 68 + scol +  8], ar[1]);
        st8(&As[srow * 68 + scol + 16], ar[2]);
        st8(&As[srow * 68 + scol + 24], ar[3]);
        st8(&Bs[srow * 68 + scol +  0], br[0]);
        st8(&Bs[srow * 68 + scol +  8], br[1]);
        st8(&Bs[srow * 68 + scol + 16], br[2]);
        st8(&Bs[srow * 68 + scol + 24], br[3]);
    };

    fetch(0);
    store_stage(0);
    __syncthreads();

    for (int kt = 0; kt < 8; ++kt) {
        const int p = kt & 1;
        unsigned short* As = shmem + p * 17408;
        unsigned short* Bs = shmem + p * 17408 + 8704;
        if (kt + 1 < 8) fetch((kt + 1) * 64);
        #pragma unroll
        for (int ks = 0; ks < 2; ++ks) {
            short8 af[4], bf[4];
            #pragma unroll
            for (int f = 0; f < 4; ++f) {
                af[f] = ld_frag(&As[(wm + f * 16 + m16) * 68 + ks * 32 + quad * 8]);
                bf[f] = ld_frag(&Bs[(wn + f * 16 + m16) * 68 + ks * 32 + quad * 8]);
            }
            #pragma unroll
            for (int fm = 0; fm < 4; ++fm)
                #pragma unroll
                for (int fn = 0; fn < 4; ++fn)
                    acc[fm][fn] = MFMA16(af[fm], bf[fn], acc[fm][fn]);
        }
        if (kt + 1 < 8) store_stage(1 - p);
        __syncthreads();
    }

    #pragma unroll
    for (int fn = 0; fn < 4; ++fn) {
        const int n = bn + wn + fn * 16 + m16;
        const float bv = bias[n];
        #pragma unroll
        for (int fm = 0; fm < 4; ++fm)
            #pragma unroll
            for (int rgi = 0; rgi < 4; ++rgi) {
                const int m = bm + wm + fm * 16 + quad * 4 + rgi;
                out[(size_t)m * EMB + n] = acc[fm][fn][rgi] + bv;
            }
    }
}

// ---------------------------------------------------------------------------
// Fused MFMA attention — R11 proven version (95 us), row-split.
//   bd[t][s] = QR[t][T-1-t+s] (s<=t) | 0 (s==t+1) | QR[t+1][s-t-2] (s>=t+2)
// LDS (u16): k@0 (2x4352) v@8704 (2x4352) rp@17408 (2x4352) ring@26112
// (64x133, [i][slot]). 69,248 B -> 2 blocks/CU.
// ---------------------------------------------------------------------------
__global__ __launch_bounds__(256)
void attn_mfma(const unsigned short* __restrict__ qg_, const unsigned short* __restrict__ kg_,
               const unsigned short* __restrict__ vtg_, const unsigned short* __restrict__ rg_,
               const float* __restrict__ rwb, const float* __restrict__ rrb,
               unsigned short* __restrict__ ctx)
{
    const int T   = T_SEQ;
    const int tb  = blockIdx.x;
    const int t0  = tb * 64;
    const int bh  = blockIdx.y;
    const int h   = bh & 7;
    const int b   = bh >> 3;
    const int tid = threadIdx.x;
    const int lane = tid & 63;
    const int w    = tid >> 6;
    const int m16  = lane & 15;
    const int quad = lane >> 4;
    const int ibase = 16 * w + quad * 4;

    __shared__ unsigned short lds[34624];
    unsigned short* ring  = lds + 26112;
    unsigned short* qrw_s = lds;
    unsigned short* qrr_s = lds + 8704;

    const unsigned short* qg  = qg_  + ((size_t)bh * T + t0) * DHEAD;
    const unsigned short* kg  = kg_  + (size_t)bh * T * DHEAD;
    const unsigned short* vtg = vtg_ + (size_t)bh * DHEAD * T;
    const unsigned short* rg  = rg_  + h * DHEAD;

    const float QSCALE = 0.125f * 1.44269504089f;
    for (int idx = tid; idx < 65 * 16; idx += 256) {
        const int row = idx >> 4, c = (idx & 15) << 2;
        ushort4v qv = {0, 0, 0, 0};
        if (t0 + row < T) qv = *(const ushort4v*)(qg + row * DHEAD + c);
        const float4 rr = *(const float4*)(rrb + h * DHEAD + c);
        qrr_s[row * 68 + c + 0] = f2b((b2f(qv[0]) + rr.x) * QSCALE);
        qrr_s[row * 68 + c + 1] = f2b((b2f(qv[1]) + rr.y) * QSCALE);
        qrr_s[row * 68 + c + 2] = f2b((b2f(qv[2]) + rr.z) * QSCALE);
        qrr_s[row * 68 + c + 3] = f2b((b2f(qv[3]) + rr.w) * QSCALE);
        if (row < 64) {
            const float4 rw = *(const float4*)(rwb + h * DHEAD + c);
            qrw_s[row * 68 + c + 0] = f2b((b2f(qv[0]) + rw.x) * QSCALE);
            qrw_s[row * 68 + c + 1] = f2b((b2f(qv[1]) + rw.y) * QSCALE);
            qrw_s[row * 68 + c + 2] = f2b((b2f(qv[2]) + rw.z) * QSCALE);
            qrw_s[row * 68 + c + 3] = f2b((b2f(qv[3]) + rw.w) * QSCALE);
        }
    }
    __syncthreads();

    short8 a_ac[2], a_qrl[2], a_qru[2];
    {
        const unsigned short* p0 = &qrw_s[(16 * w + m16) * 68 + quad * 8];
        a_ac[0]  = ld_frag(p0);  a_ac[1]  = ld_frag(p0 + 32);
        const unsigned short* p1 = &qrr_s[(16 * w + m16) * 68 + quad * 8];
        a_qrl[0] = ld_frag(p1);  a_qrl[1] = ld_frag(p1 + 32);
        const unsigned short* p2 = &qrr_s[(16 * w + 1 + m16) * 68 + quad * 8];
        a_qru[0] = ld_frag(p2);  a_qru[1] = ld_frag(p2 + 32);
    }

    const int srow0 = tid >> 3,          scol0 = (tid & 7) * 8;
    const int srow1 = (tid + 256) >> 3,  scol1 = (tid & 7) * 8;

    ushort8 kr[2], vr[2], rr8[2];
    auto prefetch = [&](int s0n) {
        const bool ln = (s0n <= t0);
        const int jb = (ln ? (s0n + T - t0 - 64) : (s0n - t0 - 65)) + 64;
        int j0 = jb + srow0; j0 = j0 < 0 ? 0 : (j0 > T - 1 ? T - 1 : j0);
        int j1 = jb + srow1; j1 = j1 < 0 ? 0 : (j1 > T - 1 ? T - 1 : j1);
        kr[0]  = *(const ushort8*)(kg + (size_t)(s0n + srow0) * DHEAD + scol0);
        kr[1]  = *(const ushort8*)(kg + (size_t)(s0n + srow1) * DHEAD + scol1);
        vr[0]  = *(const ushort8*)(vtg + (size_t)srow0 * T + s0n + scol0);
        vr[1]  = *(const ushort8*)(vtg + (size_t)srow1 * T + s0n + scol1);
        rr8[0] = *(const ushort8*)(rg + (size_t)j0 * EMB + scol0);
        rr8[1] = *(const ushort8*)(rg + (size_t)j1 * EMB + scol1);
    };
    auto store_bufs = [&](int q) {
        unsigned short* kb = lds + q * 4352;
        unsigned short* vb = lds + 8704 + q * 4352;
        unsigned short* rb = lds + 17408 + q * 4352;
        st8(&kb[srow0 * 68 + scol0], kr[0]);
        st8(&kb[srow1 * 68 + scol1], kr[1]);
        st8(&vb[srow0 * 68 + scol0], vr[0]);
        st8(&vb[srow1 * 68 + scol1], vr[1]);
        st8(&rb[srow0 * 68 + scol0], rr8[0]);
        st8(&rb[srow1 * 68 + scol1], rr8[1]);
    };
    auto stage_to = [&](unsigned short* dstb, int jbase) {
        #pragma unroll
        for (int idx = tid; idx < 512; idx += 256) {
            const int row = idx >> 3, c = (idx & 7) * 8;
            int j = jbase + row; j = j < 0 ? 0 : (j > T - 1 ? T - 1 : j);
            st8(&dstb[row * 68 + c], *(const ushort8*)(rg + (size_t)j * EMB + c));
        }
    };
    auto qr_half = [&](const unsigned short* rsb, const short8* aq, int slotbase) {
        #pragma unroll
        for (int cc = 0; cc < 4; ++cc) {
            floatx4 q4 = (floatx4){0.f, 0.f, 0.f, 0.f};
            #pragma unroll
            for (int ks = 0; ks < 2; ++ks) {
                short8 bfr = ld_frag(&rsb[(16 * cc + m16) * 68 + ks * 32 + quad * 8]);
                q4 = MFMA16(aq[ks], bfr, q4);
            }
            #pragma unroll
            for (int rgi = 0; rgi < 4; ++rgi)
                ring[(ibase + rgi) * 133 + slotbase + 16 * cc + m16] = f2bt(q4[rgi]);
        }
    };

    floatx4 O[4];
    float lrun[4];
    #pragma unroll
    for (int ct = 0; ct < 4; ++ct) O[ct] = (floatx4){0.f, 0.f, 0.f, 0.f};
    #pragma unroll
    for (int rgi = 0; rgi < 4; ++rgi) lrun[rgi] = 0.f;

    {
        stage_to(lds + 17408 + 4352, T - t0 - 64);
        prefetch(0);
        __syncthreads();
        qr_half(lds + 17408 + 4352, a_qrl, 0);
        store_bufs(0);
        __syncthreads();
    }

    for (int na = 0; na < T / 64; ++na) {
        const int s0 = na * 64;
        const int p = na & 1;
        unsigned short* kb = lds + p * 4352;
        unsigned short* vb = lds + 8704 + p * 4352;
        unsigned short* rp = lds + 17408 + p * 4352;
        const bool lower = (s0 <= t0);
        const int nph    = lower ? (s0 >> 6) : ((s0 - t0) >> 6);
        const int rbase  = (nph & 1) * 64;
        const int wbase  = 64 - rbase;
        const bool hasNext = (na + 1 < T / 64);

        floatx4 acf[4];
        #pragma unroll
        for (int ct = 0; ct < 4; ++ct) {
            acf[ct] = (floatx4){0.f, 0.f, 0.f, 0.f};
            #pragma unroll
            for (int ks = 0; ks < 2; ++ks) {
                short8 bfr = ld_frag(&kb[(16 * ct + m16) * 68 + ks * 32 + quad * 8]);
                acf[ct] = MFMA16(a_ac[ks], bfr, acf[ct]);
            }
        }
        qr_half(rp, lower ? a_qrl : a_qru, wbase);
        if (hasNext) prefetch(s0 + 64);
        __syncthreads();                       // B1

        if (s0 != t0) {
            #pragma unroll
            for (int ct = 0; ct < 4; ++ct) {
                #pragma unroll
                for (int rgi = 0; rgi < 4; ++rgi) {
                    const int i = ibase + rgi;
                    const int slot = ((63 - i + 16 * ct + m16) + rbase) & 127;
                    acf[ct][rgi] += b2f(ring[i * 133 + slot]);
                }
            }
            if (s0 == t0 + 64 && lane == 48 && w == 3)
                acf[0][3] -= b2f(ring[63 * 133 + (rbase & 127)]);
        } else {
            #pragma unroll
            for (int ct = 0; ct < 4; ++ct) {
                #pragma unroll
                for (int rgi = 0; rgi < 4; ++rgi) {
                    const int i = ibase + rgi, u = 16 * ct + m16;
                    if (u <= i) acf[ct][rgi] += b2f(ring[i * 133 + (((63 - i + u) + rbase) & 127)]);
                }
            }
            unsigned short* rpo = lds + 17408 + (1 - p) * 4352;
            __syncthreads();                   // Bd1
            stage_to(rpo, -1);
            __syncthreads();                   // Bd2
            qr_half(rpo, a_qru, 64);
            __syncthreads();                   // Bd3
            #pragma unroll
            for (int ct = 0; ct < 4; ++ct) {
                #pragma unroll
                for (int rgi = 0; rgi < 4; ++rgi) {
                    const int i = ibase + rgi, u = 16 * ct + m16;
                    if (u >= i + 2) acf[ct][rgi] += b2f(ring[i * 133 + 63 - i + u]);
                }
            }
        }

        #pragma unroll
        for (int rgi = 0; rgi < 4; ++rgi) {
            #pragma unroll
            for (int ct = 0; ct < 4; ++ct) {
                const float pv = exp2f(acf[ct][rgi]);
                acf[ct][rgi] = pv;
                lrun[rgi] += pv;
            }
        }
        #pragma unroll
        for (int ct = 0; ct < 4; ++ct)
            #pragma unroll
            for (int rgi = 0; rgi < 4; ++rgi)
                rp[(ibase + rgi) * 68 + 16 * ct + m16] = f2bt(acf[ct][rgi]);
        if (hasNext) store_bufs(1 - p);
        __syncthreads();                       // B2

        short8 ap[2];
        {
            const unsigned short* pp = &rp[(16 * w + m16) * 68 + quad * 8];
            ap[0] = ld_frag(pp); ap[1] = ld_frag(pp + 32);
        }
        #pragma unroll
        for (int ct = 0; ct < 4; ++ct) {
            #pragma unroll
            for (int ks = 0; ks < 2; ++ks) {
                short8 bfr = ld_frag(&vb[(16 * ct + m16) * 68 + ks * 32 + quad * 8]);
                O[ct] = MFMA16(ap[ks], bfr, O[ct]);
            }
        }
    }

    #pragma unroll
    for (int rgi = 0; rgi < 4; ++rgi) {
        float l = lrun[rgi];
        #pragma unroll
        for (int off = 1; off < 16; off <<= 1)
            l += __shfl_xor(l, off);
        const float inv = 1.f / l;
        const int t = t0 + ibase + rgi;
        #pragma unroll
        for (int ct = 0; ct < 4; ++ct)
            ctx[((size_t)t * BATCH + b) * EMB + h * DHEAD + 16 * ct + m16] = f2bt(O[ct][rgi] * inv);
    }
}

// ---------------------------------------------------------------------------
// Workspace (ushort offsets), 15,990,784 ush = 31.98 MB:
//   0 inb | 2097152 posb | 3145728 w_inb | 3932160 w_posb | 4194304 free |
//   6291456 w_outb | 6553600 q_s | 8650752 k_s | 10747904 vT | 12845056 r_b |
//   13893632 ctx_b
// ---------------------------------------------------------------------------
extern "C" void kernel_launch(void* const* d_in, const int* in_sizes, int n_in,
                              void* d_out, int out_size, void* d_ws, size_t ws_size,
                              hipStream_t stream)
{
    const float* input = (const float*)d_in[0];
    const float* pos   = (const float*)d_in[1];
    const float* w_in  = (const float*)d_in[2];
    const float* w_out = (const float*)d_in[3];
    const float* w_pos = (const float*)d_in[4];
    const float* b_in  = (const float*)d_in[5];
    const float* b_out = (const float*)d_in[6];
    const float* b_pos = (const float*)d_in[7];
    const float* rwb   = (const float*)d_in[8];
    const float* rrb   = (const float*)d_in[9];

    unsigned short* ws     = (unsigned short*)d_ws;
    unsigned short* inb    = ws;
    unsigned short* posb   = ws + 2097152;
    unsigned short* w_inb  = ws + 3145728;
    unsigned short* w_posb = ws + 3932160;
    unsigned short* w_outb = ws + 6291456;
    unsigned short* q_s    = ws + 6553600;
    unsigned short* k_s    = ws + 8650752;
    unsigned short* vT     = ws + 10747904;
    unsigned short* r_b    = ws + 12845056;
    unsigned short* ctx_b  = ws + 13893632;

    cvt_all<<<4352, 256, 0, stream>>>(input, pos, w_in, w_pos, w_out,
                                      inb, posb, w_inb, w_posb, w_outb);
    gemm_qkv_pos<<<448, 256, 0, stream>>>(inb, w_inb, b_in, posb, w_posb, b_pos,
                                          q_s, k_s, vT, r_b);
    attn_mfma<<<dim3(32, 16), 256, 0, stream>>>(q_s, k_s, vT, r_b, rwb, rrb, ctx_b);
    gemm_out<<<dim3(4, 32), 256, 0, stream>>>(ctx_b, w_outb, b_out, (float*)d_out);
}